// Round 1
// baseline (58.846 us; speedup 1.0000x reference)
//
#include <hip/hip_runtime.h>
#include <hip/hip_bf16.h>

#define OUT_N 8192
#define IN_K  8192
#define M_ROWS 64
#define NCHUNK 4
#define KC (IN_K / NCHUNK)   // 2048 k per chunk

typedef __attribute__((ext_vector_type(8))) short  bf16x8;
typedef __attribute__((ext_vector_type(4))) float  f32x4;
typedef __attribute__((ext_vector_type(4))) int    int4v;
typedef __attribute__((ext_vector_type(4))) float  float4v;

__device__ const float NF4_TAB[16] = {
  -1.0f, -0.6961928009986877f, -0.5250730514526367f, -0.39491748809814453f,
  -0.28444138169288635f, -0.18477343022823334f, -0.09105003625154495f, 0.0f,
  0.07958029955625534f, 0.16093020141124725f, 0.24611230850219726f,
  0.33791524171829224f, 0.44070982933044434f, 0.5626170039176941f,
  0.7229568362236023f, 1.0f };

static __device__ __forceinline__ unsigned short f2bf(float f) {
  union { __hip_bfloat16 h; unsigned short s; } u;
  u.h = __float2bfloat16(f);
  return u.s;
}

// Repack x (fp32 [64][8192]) into bf16 MFMA A-fragment order:
// xf[((ks*4 + mt)*64 + lane)*8 + j] = bf16(x[mt*16 + (lane&15)][ks*32 + (lane>>4)*8 + j])
__global__ __launch_bounds__(256) void qlin_prep(const float* __restrict__ x,
                                                 unsigned short* __restrict__ xf) {
  int idx = blockIdx.x * 256 + threadIdx.x;
  if (idx >= M_ROWS * IN_K) return;
  int m = idx >> 13;          // row 0..63
  int k = idx & (IN_K - 1);   // col 0..8191
  int mt = m >> 4, ri = m & 15;
  int ks = k >> 5, kbb = (k >> 3) & 3, j = k & 7;
  int lane = kbb * 16 + ri;
  xf[(((ks * 4 + mt) * 64 + lane) << 3) + j] = f2bf(x[idx]);
}

// Fused NF4 dequant + GEMM. Grid = 128 col-tiles * 4 K-chunks.
// Wave w owns columns [ntile*64 + w*16, +16), all 64 x-rows, K-chunk of 2048.
__global__ __launch_bounds__(256) void qlin_main(
    const int*   __restrict__ packed,
    const float* __restrict__ absmax,
    const unsigned short* __restrict__ xf,
    float*       __restrict__ parts) {
  __shared__ float lut[16];
  if (threadIdx.x < 16) lut[threadIdx.x] = NF4_TAB[threadIdx.x];
  __syncthreads();

  const int l     = threadIdx.x & 63;
  const int w     = threadIdx.x >> 6;        // wave 0..3
  const int ntile = blockIdx.x >> 2;         // 0..127
  const int chunk = blockIdx.x & 3;          // 0..3
  const int col   = ntile * 64 + w * 16 + (l & 15);
  const int kb    = l >> 4;                  // k-block 0..3 within a k-step
  const int kc0   = chunk * KC;              // chunk k base

  f32x4 acc0 = {0.f,0.f,0.f,0.f}, acc1 = {0.f,0.f,0.f,0.f};
  f32x4 acc2 = {0.f,0.f,0.f,0.f}, acc3 = {0.f,0.f,0.f,0.f};

  // packed int index for (col, k) = col*4096 + k/2 ; per kstep we need 16 ints, lane takes 4
  const int4v* pptr = (const int4v*)(packed + (size_t)col * (IN_K / 2) + kc0 / 2);
  const int ksg0 = kc0 >> 5;                 // global k-step base
  const int abase = col * 128 + (kc0 >> 6);  // absmax block base for this col/chunk

  float amax = 0.f;
  #pragma unroll 2
  for (int ks = 0; ks < KC / 32; ++ks) {
    if ((ks & 1) == 0) amax = absmax[abase + (ks >> 1)];

    int4v pk = pptr[ks * 4 + kb];            // 4 int32 = 4 bytes of codes = 8 weights
    bf16x8 b;
    #pragma unroll
    for (int i = 0; i < 4; ++i) {
      int v = pk[i];
      float lo = lut[v & 15] * amax;         // element 2i  (low nibble)
      float hi = lut[(v >> 4) & 15] * amax;  // element 2i+1 (high nibble)
      b[2 * i]     = (short)f2bf(lo);
      b[2 * i + 1] = (short)f2bf(hi);
    }

    const unsigned short* xp = xf + (size_t)(ksg0 + ks) * 2048 + l * 8;
    bf16x8 a0 = *(const bf16x8*)(xp + 0 * 512);
    bf16x8 a1 = *(const bf16x8*)(xp + 1 * 512);
    bf16x8 a2 = *(const bf16x8*)(xp + 2 * 512);
    bf16x8 a3 = *(const bf16x8*)(xp + 3 * 512);

    acc0 = __builtin_amdgcn_mfma_f32_16x16x32_bf16(a0, b, acc0, 0, 0, 0);
    acc1 = __builtin_amdgcn_mfma_f32_16x16x32_bf16(a1, b, acc1, 0, 0, 0);
    acc2 = __builtin_amdgcn_mfma_f32_16x16x32_bf16(a2, b, acc2, 0, 0, 0);
    acc3 = __builtin_amdgcn_mfma_f32_16x16x32_bf16(a3, b, acc3, 0, 0, 0);
  }

  // store partial tile: D mapping col=lane&15, row=(lane>>4)*4+reg
  float* po = parts + (size_t)chunk * M_ROWS * OUT_N;
  const int rbase = kb * 4;
  #pragma unroll
  for (int r = 0; r < 4; ++r)
    po[(size_t)(0 * 16 + rbase + r) * OUT_N + col] = acc0[r];
  #pragma unroll
  for (int r = 0; r < 4; ++r)
    po[(size_t)(1 * 16 + rbase + r) * OUT_N + col] = acc1[r];
  #pragma unroll
  for (int r = 0; r < 4; ++r)
    po[(size_t)(2 * 16 + rbase + r) * OUT_N + col] = acc2[r];
  #pragma unroll
  for (int r = 0; r < 4; ++r)
    po[(size_t)(3 * 16 + rbase + r) * OUT_N + col] = acc3[r];
}

__global__ __launch_bounds__(256) void qlin_reduce(
    const float* __restrict__ parts,
    const float* __restrict__ bias,
    float*       __restrict__ out) {
  const int TOT4 = M_ROWS * OUT_N / 4;   // 131072
  int i4 = blockIdx.x * 256 + threadIdx.x;
  if (i4 >= TOT4) return;
  const float4v* p = (const float4v*)parts;
  float4v s0 = p[i4];
  float4v s1 = p[i4 + TOT4];
  float4v s2 = p[i4 + 2 * TOT4];
  float4v s3 = p[i4 + 3 * TOT4];
  float4v bb = ((const float4v*)bias)[i4 & (OUT_N / 4 - 1)];
  float4v r = s0 + s1 + s2 + s3 + bb;
  ((float4v*)out)[i4] = r;
}

extern "C" void kernel_launch(void* const* d_in, const int* in_sizes, int n_in,
                              void* d_out, int out_size, void* d_ws, size_t ws_size,
                              hipStream_t stream) {
  const float* x      = (const float*)d_in[0];
  const int*   packed = (const int*)d_in[1];
  const float* absmax = (const float*)d_in[2];
  const float* bias   = (const float*)d_in[3];
  float* out = (float*)d_out;

  unsigned short* xf = (unsigned short*)d_ws;                 // 1 MB
  float* parts = (float*)((char*)d_ws + (1 << 20));           // 4 * 2 MB

  qlin_prep<<<(M_ROWS * IN_K + 255) / 256, 256, 0, stream>>>(x, xf);
  qlin_main<<<(OUT_N / 64) * NCHUNK, 256, 0, stream>>>(packed, absmax, xf, parts);
  qlin_reduce<<<(M_ROWS * OUT_N / 4 + 255) / 256, 256, 0, stream>>>(parts, bias, out);
}

// Round 2
// 51.856 us; speedup vs baseline: 1.1348x; 1.1348x over previous
//
#include <hip/hip_runtime.h>
#include <hip/hip_bf16.h>

#define OUT_N 8192
#define IN_K  8192
#define M_ROWS 64

typedef __attribute__((ext_vector_type(8))) short  bf16x8;
typedef __attribute__((ext_vector_type(4))) float  f32x4;
typedef __attribute__((ext_vector_type(4))) int    int4v;

__device__ const float NF4_TAB[16] = {
  -1.0f, -0.6961928009986877f, -0.5250730514526367f, -0.39491748809814453f,
  -0.28444138169288635f, -0.18477343022823334f, -0.09105003625154495f, 0.0f,
  0.07958029955625534f, 0.16093020141124725f, 0.24611230850219726f,
  0.33791524171829224f, 0.44070982933044434f, 0.5626170039176941f,
  0.7229568362236023f, 1.0f };

static __device__ __forceinline__ unsigned short f2bf(float f) {
  union { __hip_bfloat16 h; unsigned short s; } u;
  u.h = __float2bfloat16(f);
  return u.s;
}

// Repack x (fp32 [64][8192]) into bf16 MFMA A-fragment order:
// xf[((ks*4 + mt)*64 + lane)*8 + j] = bf16(x[mt*16 + (lane&15)][ks*32 + (lane>>4)*8 + j])
__global__ __launch_bounds__(256) void qlin_prep(const float* __restrict__ x,
                                                 unsigned short* __restrict__ xf) {
  int idx = blockIdx.x * 256 + threadIdx.x;
  if (idx >= M_ROWS * IN_K) return;
  int m = idx >> 13;          // row 0..63
  int k = idx & (IN_K - 1);   // col 0..8191
  int mt = m >> 4, ri = m & 15;
  int ks = k >> 5, kbb = (k >> 3) & 3, j = k & 7;
  int lane = kbb * 16 + ri;
  xf[(((ks * 4 + mt) * 64 + lane) << 3) + j] = f2bf(x[idx]);
}

// Fused NF4 dequant + GEMM. Grid = 128 col-tiles * NC K-chunks.
// Wave w owns columns [ntile*64 + w*16, +16), all 64 x-rows, K-chunk of IN_K/NC.
template<int NC>
__global__ __launch_bounds__(256) void qlin_main(
    const int*   __restrict__ packed,
    const float* __restrict__ absmax,
    const unsigned short* __restrict__ xf,
    float*       __restrict__ parts) {
  constexpr int KCn = IN_K / NC;      // k per chunk
  constexpr int NIT = KCn / 32;       // k-steps per chunk
  constexpr int LOG = (NC == 8) ? 3 : 2;

  __shared__ float lut[16];
  if (threadIdx.x < 16) lut[threadIdx.x] = NF4_TAB[threadIdx.x];
  __syncthreads();

  const int l     = threadIdx.x & 63;
  const int w     = threadIdx.x >> 6;        // wave 0..3
  const int ntile = blockIdx.x >> LOG;       // 0..127
  const int chunk = blockIdx.x & (NC - 1);   // 0..NC-1
  const int col   = ntile * 64 + w * 16 + (l & 15);
  const int kb    = l >> 4;                  // k-block 0..3 within a k-step
  const int kc0   = chunk * KCn;             // chunk k base

  const int4v* pptr = (const int4v*)(packed + (size_t)col * (IN_K / 2) + kc0 / 2);
  const int ksg0 = kc0 >> 5;                 // global k-step base
  const float* aptr = absmax + col * 128 + (kc0 >> 6);

  f32x4 acc[4] = {{0.f,0.f,0.f,0.f},{0.f,0.f,0.f,0.f},{0.f,0.f,0.f,0.f},{0.f,0.f,0.f,0.f}};

  // --- software pipeline: packed 4 k-steps ahead, xf 1 ahead, absmax 1 group ahead
  int4v pk[4];
  #pragma unroll
  for (int i = 0; i < 4; ++i) pk[i] = pptr[i * 4 + kb];

  bf16x8 A[2][4];
  {
    const unsigned short* xp = xf + (size_t)ksg0 * 2048 + l * 8;
    #pragma unroll
    for (int mt = 0; mt < 4; ++mt) A[0][mt] = *(const bf16x8*)(xp + mt * 512);
  }
  float am0 = aptr[0], am1 = aptr[1];

  for (int ks0 = 0; ks0 < NIT; ks0 += 4) {
    float cam0 = am0, cam1 = am1;
    {
      int ia = (ks0 >> 1) + 2, ib = (ks0 >> 1) + 3;
      if (ia > NIT / 2 - 1) ia = NIT / 2 - 1;
      if (ib > NIT / 2 - 1) ib = NIT / 2 - 1;
      am0 = aptr[ia]; am1 = aptr[ib];
    }
    #pragma unroll
    for (int u = 0; u < 4; ++u) {
      const int ks = ks0 + u;
      int4v cur = pk[u];
      // prefetch packed 4 steps ahead (clamped; uniform-per-lane index math)
      {
        int nk = (ks + 4 <= NIT - 1) ? ks + 4 : NIT - 1;
        pk[u] = pptr[nk * 4 + kb];
      }
      // prefetch A-fragments for ks+1 into the other buffer
      {
        int na = (ks + 1 <= NIT - 1) ? ks + 1 : NIT - 1;
        const unsigned short* xp = xf + (size_t)(ksg0 + na) * 2048 + l * 8;
        #pragma unroll
        for (int mt = 0; mt < 4; ++mt)
          A[(u + 1) & 1][mt] = *(const bf16x8*)(xp + mt * 512);
      }
      const float amax = (u < 2) ? cam0 : cam1;
      bf16x8 b;
      #pragma unroll
      for (int i = 0; i < 4; ++i) {
        int v = cur[i];
        float lo = lut[v & 15] * amax;         // element 2i  (low nibble)
        float hi = lut[(v >> 4) & 15] * amax;  // element 2i+1 (high nibble)
        b[2 * i]     = (short)f2bf(lo);
        b[2 * i + 1] = (short)f2bf(hi);
      }
      #pragma unroll
      for (int mt = 0; mt < 4; ++mt)
        acc[mt] = __builtin_amdgcn_mfma_f32_16x16x32_bf16(A[u & 1][mt], b, acc[mt], 0, 0, 0);
    }
  }

  // store partial tile: D mapping col=lane&15, row=(lane>>4)*4+reg
  float* po = parts + (size_t)chunk * M_ROWS * OUT_N;
  const int rbase = kb * 4;
  #pragma unroll
  for (int mt = 0; mt < 4; ++mt) {
    #pragma unroll
    for (int r = 0; r < 4; ++r)
      po[(size_t)(mt * 16 + rbase + r) * OUT_N + col] = acc[mt][r];
  }
}

template<int NC>
__global__ __launch_bounds__(256) void qlin_reduce(
    const float* __restrict__ parts,
    const float* __restrict__ bias,
    float*       __restrict__ out) {
  const int TOT4 = M_ROWS * OUT_N / 4;   // 131072
  int i4 = blockIdx.x * 256 + threadIdx.x;
  if (i4 >= TOT4) return;
  const f32x4* p = (const f32x4*)parts;
  f32x4 s = p[i4];
  #pragma unroll
  for (int c = 1; c < NC; ++c) s += p[i4 + c * TOT4];
  f32x4 bb = ((const f32x4*)bias)[i4 & (OUT_N / 4 - 1)];
  ((f32x4*)out)[i4] = s + bb;
}

extern "C" void kernel_launch(void* const* d_in, const int* in_sizes, int n_in,
                              void* d_out, int out_size, void* d_ws, size_t ws_size,
                              hipStream_t stream) {
  const float* x      = (const float*)d_in[0];
  const int*   packed = (const int*)d_in[1];
  const float* absmax = (const float*)d_in[2];
  const float* bias   = (const float*)d_in[3];
  float* out = (float*)d_out;

  unsigned short* xf = (unsigned short*)d_ws;                 // 1 MB
  float* parts = (float*)((char*)d_ws + (1 << 20));           // NC * 2 MB

  qlin_prep<<<(M_ROWS * IN_K + 255) / 256, 256, 0, stream>>>(x, xf);

  const size_t need8 = (size_t)(1 << 20) + (size_t)8 * M_ROWS * OUT_N * sizeof(float);
  if (ws_size >= need8) {
    qlin_main<8><<<(OUT_N / 64) * 8, 256, 0, stream>>>(packed, absmax, xf, parts);
    qlin_reduce<8><<<(M_ROWS * OUT_N / 4 + 255) / 256, 256, 0, stream>>>(parts, bias, out);
  } else {
    qlin_main<4><<<(OUT_N / 64) * 4, 256, 0, stream>>>(packed, absmax, xf, parts);
    qlin_reduce<4><<<(M_ROWS * OUT_N / 4 + 255) / 256, 256, 0, stream>>>(parts, bias, out);
  }
}

// Round 3
// 49.370 us; speedup vs baseline: 1.1919x; 1.0504x over previous
//
#include <hip/hip_runtime.h>
#include <hip/hip_bf16.h>

#define OUT_N 8192
#define IN_K  8192
#define M_ROWS 64

typedef __attribute__((ext_vector_type(8))) short  bf16x8;
typedef __attribute__((ext_vector_type(4))) float  f32x4;
typedef __attribute__((ext_vector_type(4))) int    int4v;

__device__ const float NF4_TAB[16] = {
  -1.0f, -0.6961928009986877f, -0.5250730514526367f, -0.39491748809814453f,
  -0.28444138169288635f, -0.18477343022823334f, -0.09105003625154495f, 0.0f,
  0.07958029955625534f, 0.16093020141124725f, 0.24611230850219726f,
  0.33791524171829224f, 0.44070982933044434f, 0.5626170039176941f,
  0.7229568362236023f, 1.0f };

static __device__ __forceinline__ unsigned short f2bf(float f) {
  union { __hip_bfloat16 h; unsigned short s; } u;
  u.h = __float2bfloat16(f);
  return u.s;
}

static __device__ __forceinline__ void gload_lds16(const void* g, void* s) {
  __builtin_amdgcn_global_load_lds((const __attribute__((address_space(1))) void*)g,
                                   (__attribute__((address_space(3))) void*)s,
                                   16, 0, 0);
}

// Repack x (fp32 [64][8192]) -> bf16 MFMA A-fragment order, fully coalesced writes.
// Element layout (shorts): xf[((ks*4 + mt)*64 + lane)*8 + j]
//   = bf16(x[mt*16 + (lane&15)][ks*32 + (lane>>4)*8 + j])
__global__ __launch_bounds__(256) void qlin_prep(const float* __restrict__ x,
                                                 unsigned short* __restrict__ xf) {
  int t = blockIdx.x * 256 + threadIdx.x;          // 0..65535 = (ks, mt, lane)
  int lane = t & 63, mt = (t >> 6) & 3, ks = t >> 8;
  int ri = lane & 15, kbb = lane >> 4;
  const float* src = x + (size_t)(mt * 16 + ri) * IN_K + ks * 32 + kbb * 8;
  f32x4 a = *(const f32x4*)src;
  f32x4 c = *(const f32x4*)(src + 4);
  bf16x8 o;
  o[0] = (short)f2bf(a[0]); o[1] = (short)f2bf(a[1]);
  o[2] = (short)f2bf(a[2]); o[3] = (short)f2bf(a[3]);
  o[4] = (short)f2bf(c[0]); o[5] = (short)f2bf(c[1]);
  o[6] = (short)f2bf(c[2]); o[7] = (short)f2bf(c[3]);
  ((bf16x8*)xf)[t] = o;
}

// Fused NF4 dequant + GEMM with LDS-staged A-fragments (lgkm/vmcnt decoupling).
// Grid = 128 col-tiles * NC K-chunks; wave w owns cols [ntile*64+w*16,+16), all 64 rows.
template<int NC>
__global__ __launch_bounds__(256, 4) void qlin_main(
    const int*   __restrict__ packed,
    const float* __restrict__ absmax,
    const unsigned short* __restrict__ xf,
    float*       __restrict__ parts) {
  constexpr int KCn  = IN_K / NC;      // k per chunk
  constexpr int NIT  = KCn / 32;       // k-steps per chunk (32 for NC=8)
  constexpr int NOUT = NIT / 8;
  constexpr int LOG  = (NC == 8) ? 3 : 2;

  __shared__ unsigned int  lut256[256];
  __shared__ unsigned char stagebuf[9 * 4096];   // 9-slot ring of 4KB k-step blocks

  {
    int t = threadIdx.x;   // 256 threads -> one entry each
    unsigned lo = f2bf(NF4_TAB[t & 15]);
    unsigned hi = f2bf(NF4_TAB[(t >> 4) & 15]);
    lut256[t] = lo | (hi << 16);
  }
  __syncthreads();

  const int l     = threadIdx.x & 63;
  const int w     = threadIdx.x >> 6;        // wave 0..3
  const int ntile = blockIdx.x >> LOG;       // 0..127
  const int chunk = blockIdx.x & (NC - 1);
  const int col   = ntile * 64 + w * 16 + (l & 15);
  const int kb    = l >> 4;                  // k-quarter within a k-step
  const int kc0   = chunk * KCn;
  const int ksg0  = kc0 >> 5;

  const int4v* pptr  = (const int4v*)(packed + (size_t)col * (IN_K / 2) + kc0 / 2);
  const f32x4* aptr4 = (const f32x4*)(absmax + col * 128 + (kc0 >> 6));
  const char*  xfb   = (const char*)xf + (size_t)ksg0 * 4096;  // this chunk's xf (bytes)

  f32x4 acc[4] = {{0.f,0.f,0.f,0.f},{0.f,0.f,0.f,0.f},{0.f,0.f,0.f,0.f},{0.f,0.f,0.f,0.f}};
  int4v pk[8];

  // ---- prologue: stage k-steps 0..7 into slots 0..7, pk 0..7, first absmax quad
  #pragma unroll
  for (int s = 0; s < 8; ++s)
    gload_lds16(xfb + s * 4096 + w * 1024 + l * 16, stagebuf + s * 4096 + w * 1024);
  #pragma unroll
  for (int i = 0; i < 8; ++i) pk[i] = pptr[i * 4 + kb];
  f32x4 am_next = aptr4[0];

  asm volatile("s_waitcnt vmcnt(15)" ::: "memory");
  __builtin_amdgcn_s_barrier();

  int rd_off = 0;            // byte offset of read slot (slot u%9)
  int st_off = 8 * 4096;     // byte offset of stage slot ((u+8)%9)

  for (int o = 0; o < NOUT; ++o) {
    const f32x4 am_cur = am_next;
    am_next = aptr4[(o + 1 < NOUT) ? (o + 1) : (NOUT - 1)];
    #pragma unroll
    for (int u8 = 0; u8 < 8; ++u8) {
      const int u = o * 8 + u8;
      // 1. A-fragment reads from the read slot (lgkmcnt only)
      const unsigned char* rp = stagebuf + rd_off + l * 16;
      bf16x8 A0 = *(const bf16x8*)(rp + 0 * 1024);
      bf16x8 A1 = *(const bf16x8*)(rp + 1 * 1024);
      bf16x8 A2 = *(const bf16x8*)(rp + 2 * 1024);
      bf16x8 A3 = *(const bf16x8*)(rp + 3 * 1024);
      // 2. dequant 8 weights from pk[u] (loaded 8 iters ago; deep vmcnt cover)
      int4v cur = pk[u8];
      const float amax = am_cur[u8 >> 1];
      bf16x8 b;
      #pragma unroll
      for (int i = 0; i < 4; ++i) {
        unsigned pair = lut256[cur[i] & 255];
        float flo = __uint_as_float(pair << 16) * amax;          // low nibble -> elem 2i
        float fhi = __uint_as_float(pair & 0xffff0000u) * amax;  // high nibble -> 2i+1
        b[2 * i]     = (short)f2bf(flo);
        b[2 * i + 1] = (short)f2bf(fhi);
      }
      // 3. MFMA
      acc[0] = __builtin_amdgcn_mfma_f32_16x16x32_bf16(A0, b, acc[0], 0, 0, 0);
      acc[1] = __builtin_amdgcn_mfma_f32_16x16x32_bf16(A1, b, acc[1], 0, 0, 0);
      acc[2] = __builtin_amdgcn_mfma_f32_16x16x32_bf16(A2, b, acc[2], 0, 0, 0);
      acc[3] = __builtin_amdgcn_mfma_f32_16x16x32_bf16(A3, b, acc[3], 0, 0, 0);
      // 4. prefetch 8 ahead: stage slot (u+8)%9 (== slot (u-1)%9, reads done last iter),
      //    and pk ring
      {
        int sk = (u + 8 < NIT) ? (u + 8) : (NIT - 1);
        gload_lds16(xfb + (size_t)sk * 4096 + w * 1024 + l * 16,
                    stagebuf + st_off + w * 1024);
        pk[u8] = pptr[sk * 4 + kb];
      }
      rd_off += 4096; if (rd_off == 9 * 4096) rd_off = 0;
      st_off += 4096; if (st_off == 9 * 4096) st_off = 0;
      // 5. counted waits (never vmcnt(0)) + raw barrier:
      //    stage(u+1) has exactly 15 younger VMEM ops here -> retired by vmcnt(15);
      //    lgkmcnt(0) ensures this wave's slot reads completed before others may
      //    overwrite the slot after the barrier.
      asm volatile("s_waitcnt vmcnt(15)" ::: "memory");
      asm volatile("s_waitcnt lgkmcnt(0)" ::: "memory");
      __builtin_amdgcn_s_barrier();
    }
  }

  // epilogue: D mapping col=lane&15, row=(lane>>4)*4+reg
  float* po = parts + (size_t)chunk * M_ROWS * OUT_N;
  const int rbase = kb * 4;
  #pragma unroll
  for (int mt = 0; mt < 4; ++mt) {
    #pragma unroll
    for (int r = 0; r < 4; ++r)
      po[(size_t)(mt * 16 + rbase + r) * OUT_N + col] = acc[mt][r];
  }
}

template<int NC>
__global__ __launch_bounds__(256) void qlin_reduce(
    const float* __restrict__ parts,
    const float* __restrict__ bias,
    float*       __restrict__ out) {
  const int TOT4 = M_ROWS * OUT_N / 4;   // 131072
  int i4 = blockIdx.x * 256 + threadIdx.x;
  if (i4 >= TOT4) return;
  const f32x4* p = (const f32x4*)parts;
  f32x4 s = p[i4];
  #pragma unroll
  for (int c = 1; c < NC; ++c) s += p[i4 + c * TOT4];
  f32x4 bb = ((const f32x4*)bias)[i4 & (OUT_N / 4 - 1)];
  ((f32x4*)out)[i4] = s + bb;
}

extern "C" void kernel_launch(void* const* d_in, const int* in_sizes, int n_in,
                              void* d_out, int out_size, void* d_ws, size_t ws_size,
                              hipStream_t stream) {
  const float* x      = (const float*)d_in[0];
  const int*   packed = (const int*)d_in[1];
  const float* absmax = (const float*)d_in[2];
  const float* bias   = (const float*)d_in[3];
  float* out = (float*)d_out;

  unsigned short* xf = (unsigned short*)d_ws;                 // 1 MB
  float* parts = (float*)((char*)d_ws + (1 << 20));           // NC * 2 MB

  qlin_prep<<<(M_ROWS * IN_K / 8 + 255) / 256, 256, 0, stream>>>(x, xf);

  const size_t need8 = (size_t)(1 << 20) + (size_t)8 * M_ROWS * OUT_N * sizeof(float);
  if (ws_size >= need8) {
    qlin_main<8><<<(OUT_N / 64) * 8, 256, 0, stream>>>(packed, absmax, xf, parts);
    qlin_reduce<8><<<(M_ROWS * OUT_N / 4 + 255) / 256, 256, 0, stream>>>(parts, bias, out);
  } else {
    qlin_main<4><<<(OUT_N / 64) * 4, 256, 0, stream>>>(packed, absmax, xf, parts);
    qlin_reduce<4><<<(M_ROWS * OUT_N / 4 + 255) / 256, 256, 0, stream>>>(parts, bias, out);
  }
}